// Round 1
// baseline (1461.417 us; speedup 1.0000x reference)
//
#include <hip/hip_runtime.h>

#define B_   32
#define NT_  1002
#define D_   128
#define H_   8
#define DK_  16
#define FF_  512
#define ROWS (B_ * NT_)          // 32064
#define NEGV (-1e9f)

// ---------------- init embeddings ----------------
__global__ __launch_bounds__(256) void init_kernel(
    const float* __restrict__ depot, const float* __restrict__ loc, const float* __restrict__ demand,
    const float* __restrict__ Wn, const float* __restrict__ bn_, const float* __restrict__ Wd,
    const float* __restrict__ bd, float* __restrict__ h) {
  int idx = blockIdx.x * 256 + threadIdx.x;
  if (idx >= ROWS * D_) return;
  int c = idx & 127;
  int row = idx >> 7;
  int b = row / NT_;
  int n = row - b * NT_;
  float v;
  if (n < 2) {
    const float* dp = depot + (b * 2 + n) * 2;
    v = dp[0] * Wd[c] + dp[1] * Wd[D_ + c] + bd[c];
  } else {
    int i = n - 2;
    const float* lp = loc + ((size_t)b * 1000 + i) * 2;
    v = lp[0] * Wn[c] + lp[1] * Wn[D_ + c] + demand[b * 1000 + i] * Wn[2 * D_ + c] + bn_[c];
  }
  h[idx] = v;
}

// ---------------- generic fp32 GEMM: C = A[M,K] @ W[K,N] (+bias)(+relu)(+residual) ----------------
template<bool BIAS, bool RELU, bool RES>
__global__ __launch_bounds__(256) void gemm_kernel(
    const float* __restrict__ A, const float* __restrict__ W,
    const float* __restrict__ bias, const float* __restrict__ R,
    float* __restrict__ C, int M, int N, int K) {
  __shared__ float As[16][68];   // [k][m], padded
  __shared__ float Bs[16][64];   // [k][n]
  int bn = blockIdx.x * 64;
  int bm = blockIdx.y * 64;
  int tid = threadIdx.x;
  int tx = tid & 15, ty = tid >> 4;
  float acc[4][4] = {};
  for (int k0 = 0; k0 < K; k0 += 16) {
    __syncthreads();
#pragma unroll
    for (int it = 0; it < 4; ++it) {
      int idx = it * 256 + tid;
      int r = idx >> 4, c = idx & 15;
      As[c][r] = A[(size_t)(bm + r) * K + k0 + c];
    }
#pragma unroll
    for (int it = 0; it < 4; ++it) {
      int idx = it * 256 + tid;
      int r = idx >> 6, c = idx & 63;
      Bs[r][c] = W[(size_t)(k0 + r) * N + bn + c];
    }
    __syncthreads();
#pragma unroll
    for (int kk = 0; kk < 16; ++kk) {
      float a0 = As[kk][ty * 4 + 0], a1 = As[kk][ty * 4 + 1];
      float a2 = As[kk][ty * 4 + 2], a3 = As[kk][ty * 4 + 3];
      float b0 = Bs[kk][tx * 4 + 0], b1 = Bs[kk][tx * 4 + 1];
      float b2 = Bs[kk][tx * 4 + 2], b3 = Bs[kk][tx * 4 + 3];
      acc[0][0] += a0 * b0; acc[0][1] += a0 * b1; acc[0][2] += a0 * b2; acc[0][3] += a0 * b3;
      acc[1][0] += a1 * b0; acc[1][1] += a1 * b1; acc[1][2] += a1 * b2; acc[1][3] += a1 * b3;
      acc[2][0] += a2 * b0; acc[2][1] += a2 * b1; acc[2][2] += a2 * b2; acc[2][3] += a2 * b3;
      acc[3][0] += a3 * b0; acc[3][1] += a3 * b1; acc[3][2] += a3 * b2; acc[3][3] += a3 * b3;
    }
  }
#pragma unroll
  for (int i = 0; i < 4; ++i) {
    int row = bm + ty * 4 + i;
    int col = bn + tx * 4;
#pragma unroll
    for (int j = 0; j < 4; ++j) {
      float v = acc[i][j];
      if (BIAS) v += bias[col + j];
      if (RELU) v = fmaxf(v, 0.f);
      if (RES)  v += R[(size_t)row * N + col + j];
      C[(size_t)row * N + col + j] = v;
    }
  }
}

// ---------------- encoder attention (flash-style, 1 thread = 1 q row, per (b,head)) ----------------
// qkv layout: [row, 384] with q=cols 0:128, k=128:256, v=256:384; head hd uses sub-cols hd*16..+16
__global__ __launch_bounds__(256) void attn_kernel(const float* __restrict__ qkv, float* __restrict__ out) {
  int bh = blockIdx.x;
  int b = bh >> 3, hd = bh & 7;
  int qn = blockIdx.y * 256 + threadIdx.x;
  bool valid = qn < NT_;
  const float* base = qkv + (size_t)b * NT_ * 384;
  float q[16];
#pragma unroll
  for (int i = 0; i < 16; ++i) q[i] = 0.f;
  if (valid) {
#pragma unroll
    for (int i = 0; i < 16; ++i) q[i] = base[(size_t)qn * 384 + hd * 16 + i] * 0.25f;
  }
  __shared__ float Ks[32][16];
  __shared__ float Vs[32][16];
  float m = -1e30f, l = 0.f;
  float acc[16];
#pragma unroll
  for (int i = 0; i < 16; ++i) acc[i] = 0.f;

  for (int t0 = 0; t0 < NT_; t0 += 32) {
    int cnt = NT_ - t0; if (cnt > 32) cnt = 32;
    __syncthreads();
#pragma unroll
    for (int it = 0; it < 2; ++it) {
      int idx = it * 256 + threadIdx.x;   // 0..511
      int r = idx >> 4, c = idx & 15;
      int kr = t0 + r;
      float kv = 0.f, vv = 0.f;
      if (kr < NT_) {
        kv = base[(size_t)kr * 384 + 128 + hd * 16 + c];
        vv = base[(size_t)kr * 384 + 256 + hd * 16 + c];
      }
      Ks[r][c] = kv; Vs[r][c] = vv;
    }
    __syncthreads();
    if (valid) {
      float s[32];
#pragma unroll
      for (int j = 0; j < 32; ++j) {
        float d = 0.f;
#pragma unroll
        for (int i = 0; i < 16; ++i) d += q[i] * Ks[j][i];
        s[j] = d;
      }
      float tm = m;
#pragma unroll
      for (int j = 0; j < 32; ++j) if (j < cnt) tm = fmaxf(tm, s[j]);
      float corr = __expf(m - tm);
      l *= corr;
#pragma unroll
      for (int i = 0; i < 16; ++i) acc[i] *= corr;
#pragma unroll
      for (int j = 0; j < 32; ++j) {
        float e = (j < cnt) ? __expf(s[j] - tm) : 0.f;
        l += e;
#pragma unroll
        for (int i = 0; i < 16; ++i) acc[i] += e * Vs[j][i];
      }
      m = tm;
    }
  }
  if (valid) {
    float inv = 1.f / l;
    size_t o = ((size_t)b * NT_ + qn) * D_ + hd * 16;
#pragma unroll
    for (int i = 0; i < 16; ++i) out[o + i] = acc[i] * inv;
  }
}

// ---------------- BN stats (two-stage, deterministic) ----------------
__global__ __launch_bounds__(256) void stats_partial(const float* __restrict__ X,
                                                     float* __restrict__ psum, float* __restrict__ psq) {
  int c = threadIdx.x & 127;
  int half = threadIdx.x >> 7;
  float s = 0.f, q = 0.f;
  for (int rp = blockIdx.x; rp < ROWS / 2; rp += 256) {
    int row = rp * 2 + half;
    float v = X[(size_t)row * D_ + c];
    s += v; q += v * v;
  }
  __shared__ float ss[256], sq2[256];
  ss[threadIdx.x] = s; sq2[threadIdx.x] = q;
  __syncthreads();
  if (threadIdx.x < 128) {
    psum[blockIdx.x * 128 + threadIdx.x] = ss[threadIdx.x] + ss[threadIdx.x + 128];
    psq[blockIdx.x * 128 + threadIdx.x]  = sq2[threadIdx.x] + sq2[threadIdx.x + 128];
  }
}

__global__ void stats_final(const float* __restrict__ psum, const float* __restrict__ psq,
                            float* __restrict__ mi) {
  int c = threadIdx.x;  // 128 threads
  float s = 0.f, q = 0.f;
  for (int p = 0; p < 256; ++p) { s += psum[p * 128 + c]; q += psq[p * 128 + c]; }
  float mean = s * (1.f / (float)ROWS);
  float var = q * (1.f / (float)ROWS) - mean * mean;
  mi[c] = mean;
  mi[128 + c] = rsqrtf(var + 1e-5f);
}

__global__ __launch_bounds__(256) void bn_apply(const float* __restrict__ X, const float* __restrict__ mi,
                                                const float* __restrict__ sc, const float* __restrict__ bi,
                                                float* __restrict__ Y) {
  int idx = blockIdx.x * 256 + threadIdx.x;
  if (idx < ROWS * D_) {
    int c = idx & 127;
    Y[idx] = sc[c] * (X[idx] - mi[c]) * mi[128 + c] + bi[c];
  }
}

// ---------------- decoder small kernels ----------------
__global__ void ge_kernel(const float* __restrict__ h, float* __restrict__ ge) {
  int b = blockIdx.x, d = threadIdx.x;  // 32 x 128
  float s = 0.f;
  for (int n = 0; n < NT_; ++n) s += h[((size_t)b * NT_ + n) * D_ + d];
  ge[b * D_ + d] = s * (1.f / (float)NT_);
}

__global__ void query_kernel(const float* __restrict__ ge, const float* __restrict__ h,
                             const float* __restrict__ Wf, const float* __restrict__ Ws,
                             float* __restrict__ qry) {
  int b = blockIdx.x, d = threadIdx.x;  // 32 x 128
  float s = 0.f;
  for (int k = 0; k < 128; ++k)
    s += ge[b * D_ + k] * Wf[k * D_ + d] + h[(size_t)b * NT_ * D_ + k] * Ws[k * D_ + d];
  qry[b * D_ + d] = s;
}

// ---------------- pointer step: glimpse attn + out-proj + logits + log_softmax ----------------
// proj layout [row, 384]: K_g = cols 0:128, V_g = 128:256, K_logit = 256:384
__global__ __launch_bounds__(256) void pointer_kernel(
    const float* __restrict__ proj, const float* __restrict__ query,
    const int* __restrict__ mask, const float* __restrict__ Wout,
    float* __restrict__ out) {
  __shared__ float sq[128];
  __shared__ float scomp[8][NT_];
  __shared__ float sgl[128];
  __shared__ float sg2[128];
  __shared__ float slog[NT_];
  __shared__ float red[256];
  __shared__ float hsum[8];
  int b = blockIdx.x;
  int tid = threadIdx.x;
  const float* P = proj + (size_t)b * NT_ * 384;
  const int* Mk = mask + b * NT_;
  if (tid < 128) sq[tid] = query[b * 128 + tid];
  __syncthreads();
  // compat per head
  for (int hd = 0; hd < 8; ++hd) {
    for (int n = tid; n < NT_; n += 256) {
      float d = 0.f;
#pragma unroll
      for (int i = 0; i < 16; ++i) d += sq[hd * 16 + i] * P[(size_t)n * 384 + hd * 16 + i];
      scomp[hd][n] = Mk[n] ? NEGV : d * 0.25f;
    }
  }
  __syncthreads();
  // per-head masked softmax (store exp, keep sums)
  for (int hd = 0; hd < 8; ++hd) {
    float mx = -1e30f;
    for (int n = tid; n < NT_; n += 256) mx = fmaxf(mx, scomp[hd][n]);
    red[tid] = mx; __syncthreads();
    for (int s = 128; s > 0; s >>= 1) { if (tid < s) red[tid] = fmaxf(red[tid], red[tid + s]); __syncthreads(); }
    mx = red[0]; __syncthreads();
    float sm = 0.f;
    for (int n = tid; n < NT_; n += 256) { float e = __expf(scomp[hd][n] - mx); scomp[hd][n] = e; sm += e; }
    red[tid] = sm; __syncthreads();
    for (int s = 128; s > 0; s >>= 1) { if (tid < s) red[tid] += red[tid + s]; __syncthreads(); }
    if (tid == 0) hsum[hd] = red[0];
    __syncthreads();
  }
  // glimpse = attn @ V  (128 threads: (hd,i))
  if (tid < 128) {
    int hd = tid >> 4, i = tid & 15;
    float g = 0.f;
    for (int n = 0; n < NT_; ++n) g += scomp[hd][n] * P[(size_t)n * 384 + 128 + hd * 16 + i];
    sgl[tid] = g / hsum[hd];
  }
  __syncthreads();
  // g2 = glimpse @ Wout
  if (tid < 128) {
    float g = 0.f;
    for (int k = 0; k < 128; ++k) g += sgl[k] * Wout[k * 128 + tid];
    sg2[tid] = g;
  }
  __syncthreads();
  // logits
  for (int n = tid; n < NT_; n += 256) {
    float d = 0.f;
    for (int c = 0; c < 128; ++c) d += sg2[c] * P[(size_t)n * 384 + 256 + c];
    d = 10.f * tanhf(d * 0.088388347648318447f);  // 1/sqrt(128)
    slog[n] = Mk[n] ? NEGV : d;
  }
  __syncthreads();
  // log_softmax
  float mx = -1e30f;
  for (int n = tid; n < NT_; n += 256) mx = fmaxf(mx, slog[n]);
  red[tid] = mx; __syncthreads();
  for (int s = 128; s > 0; s >>= 1) { if (tid < s) red[tid] = fmaxf(red[tid], red[tid + s]); __syncthreads(); }
  mx = red[0]; __syncthreads();
  float sm = 0.f;
  for (int n = tid; n < NT_; n += 256) sm += __expf(slog[n] - mx);
  red[tid] = sm; __syncthreads();
  for (int s = 128; s > 0; s >>= 1) { if (tid < s) red[tid] += red[tid + s]; __syncthreads(); }
  float lse = mx + logf(red[0]);
  for (int n = tid; n < NT_; n += 256) out[(size_t)b * NT_ + n] = slog[n] - lse;
}

// ---------------- launcher ----------------
extern "C" void kernel_launch(void* const* d_in, const int* in_sizes, int n_in,
                              void* d_out, int out_size, void* d_ws, size_t ws_size,
                              hipStream_t stream) {
  const float* depot        = (const float*)d_in[0];
  const float* loc          = (const float*)d_in[1];
  const float* demand       = (const float*)d_in[2];
  const int*   mask         = (const int*)d_in[3];
  const float* W_init_node  = (const float*)d_in[4];
  const float* b_init_node  = (const float*)d_in[5];
  const float* W_init_depot = (const float*)d_in[6];
  const float* b_init_depot = (const float*)d_in[7];
  const float* enc_Wqkv     = (const float*)d_in[8];
  const float* enc_Wo       = (const float*)d_in[9];
  const float* enc_W1       = (const float*)d_in[10];
  const float* enc_b1       = (const float*)d_in[11];
  const float* enc_W2       = (const float*)d_in[12];
  const float* enc_b2       = (const float*)d_in[13];
  const float* bn1_s        = (const float*)d_in[14];
  const float* bn1_b        = (const float*)d_in[15];
  const float* bn2_s        = (const float*)d_in[16];
  const float* bn2_b        = (const float*)d_in[17];
  const float* W_proj       = (const float*)d_in[18];
  const float* W_fixed      = (const float*)d_in[19];
  const float* W_step       = (const float*)d_in[20];
  const float* W_out        = (const float*)d_in[21];
  float* out = (float*)d_out;

  float* ws  = (float*)d_ws;
  float* h   = ws;                                  // ROWS*128
  float* xb  = h + (size_t)ROWS * D_;               // ROWS*128
  float* big = xb + (size_t)ROWS * D_;              // ROWS*512 (qkv/ff1/proj)
  float* ab  = big + (size_t)ROWS * 384;            // ROWS*128 (tail of big, disjoint from qkv cols)
  float* psum = big + (size_t)ROWS * FF_;           // 256*128
  float* psq  = psum + 256 * 128;                   // 256*128
  float* mi   = psq + 256 * 128;                    // 256
  float* ge   = mi + 256;                           // 32*128
  float* qry  = ge + 32 * 128;                      // 32*128

  init_kernel<<<(ROWS * D_ + 255) / 256, 256, 0, stream>>>(
      depot, loc, demand, W_init_node, b_init_node, W_init_depot, b_init_depot, h);

  for (int l = 0; l < 2; ++l) {
    // qkv = h @ Wqkv[l]  -> big (cols 0:384 of the 512-wide buffer region, packed [ROWS,384])
    gemm_kernel<false, false, false><<<dim3(6, 501), 256, 0, stream>>>(
        h, enc_Wqkv + (size_t)l * D_ * 3 * D_, nullptr, nullptr, big, ROWS, 384, D_);
    attn_kernel<<<dim3(256, 4), 256, 0, stream>>>(big, ab);
    // x = ab @ Wo[l] + h  -> xb
    gemm_kernel<false, false, true><<<dim3(2, 501), 256, 0, stream>>>(
        ab, enc_Wo + (size_t)l * D_ * D_, nullptr, h, xb, ROWS, D_, D_);
    stats_partial<<<256, 256, 0, stream>>>(xb, psum, psq);
    stats_final<<<1, 128, 0, stream>>>(psum, psq, mi);
    bn_apply<<<(ROWS * D_ + 255) / 256, 256, 0, stream>>>(xb, mi, bn1_s + l * D_, bn1_b + l * D_, h);
    // ff1 = relu(h @ W1[l] + b1[l]) -> big [ROWS,512]
    gemm_kernel<true, true, false><<<dim3(8, 501), 256, 0, stream>>>(
        h, enc_W1 + (size_t)l * D_ * FF_, enc_b1 + (size_t)l * FF_, nullptr, big, ROWS, FF_, D_);
    // x = ff1 @ W2[l] + b2[l] + h -> xb
    gemm_kernel<true, false, true><<<dim3(2, 501), 256, 0, stream>>>(
        big, enc_W2 + (size_t)l * FF_ * D_, enc_b2 + (size_t)l * D_, h, xb, ROWS, D_, FF_);
    stats_partial<<<256, 256, 0, stream>>>(xb, psum, psq);
    stats_final<<<1, 128, 0, stream>>>(psum, psq, mi);
    bn_apply<<<(ROWS * D_ + 255) / 256, 256, 0, stream>>>(xb, mi, bn2_s + l * D_, bn2_b + l * D_, h);
  }

  // proj = h @ W_proj -> big [ROWS,384]
  gemm_kernel<false, false, false><<<dim3(6, 501), 256, 0, stream>>>(
      h, W_proj, nullptr, nullptr, big, ROWS, 384, D_);
  ge_kernel<<<32, 128, 0, stream>>>(h, ge);
  query_kernel<<<32, 128, 0, stream>>>(ge, h, W_fixed, W_step, qry);
  pointer_kernel<<<32, 256, 0, stream>>>(big, qry, mask, W_out, out);
}

// Round 2
// 614.849 us; speedup vs baseline: 2.3769x; 2.3769x over previous
//
#include <hip/hip_runtime.h>

#define B_   32
#define NT_  1002
#define D_   128
#define H_   8
#define FF_  512
#define ROWS (B_ * NT_)          // 32064 = 501*64
#define NEGV (-1e9f)

typedef __bf16 bf16;
typedef __bf16 bf16x8 __attribute__((ext_vector_type(8)));
typedef __bf16 bf16x4 __attribute__((ext_vector_type(4)));
typedef float  f32x4  __attribute__((ext_vector_type(4)));
typedef float  f32x16 __attribute__((ext_vector_type(16)));

// ---------------- weight prep: transpose + convert to bf16 [n][k] ----------------
#define SZ_QKV (2*384*128)
#define SZ_WO  (2*128*128)
#define SZ_W1  (2*512*128)
#define SZ_W2  (2*128*512)
#define SZ_PROJ (384*128)

__global__ __launch_bounds__(256) void prep_w(
    const float* __restrict__ qkv, const float* __restrict__ wo, const float* __restrict__ w1,
    const float* __restrict__ w2, const float* __restrict__ proj, bf16* __restrict__ out) {
  int i = blockIdx.x * 256 + threadIdx.x;
  int j = i;
  float v;
  if (j < SZ_QKV) {
    int l = j / 49152, r = j % 49152; int n = r >> 7, k = r & 127;
    v = qkv[((size_t)l * 128 + k) * 384 + n];
  } else {
    j -= SZ_QKV;
    if (j < SZ_WO) {
      int l = j >> 14, r = j & 16383; int n = r >> 7, k = r & 127;
      v = wo[((size_t)l * 128 + k) * 128 + n];
    } else {
      j -= SZ_WO;
      if (j < SZ_W1) {
        int l = j >> 16, r = j & 65535; int n = r >> 7, k = r & 127;
        v = w1[((size_t)l * 128 + k) * 512 + n];
      } else {
        j -= SZ_W1;
        if (j < SZ_W2) {
          int l = j >> 16, r = j & 65535; int n = r >> 9, k = r & 511;
          v = w2[((size_t)l * 512 + k) * 128 + n];
        } else {
          j -= SZ_W2;
          int n = j >> 7, k = j & 127;
          v = proj[(size_t)k * 384 + n];
        }
      }
    }
  }
  out[i] = (bf16)v;
}

// ---------------- init embeddings (fp32 + bf16 shadow) ----------------
__global__ __launch_bounds__(256) void init_kernel(
    const float* __restrict__ depot, const float* __restrict__ loc, const float* __restrict__ demand,
    const float* __restrict__ Wn, const float* __restrict__ bn_, const float* __restrict__ Wd,
    const float* __restrict__ bd, float* __restrict__ h, bf16* __restrict__ hb) {
  int idx = blockIdx.x * 256 + threadIdx.x;
  if (idx >= ROWS * D_) return;
  int c = idx & 127;
  int row = idx >> 7;
  int b = row / NT_;
  int n = row - b * NT_;
  float v;
  if (n < 2) {
    const float* dp = depot + (b * 2 + n) * 2;
    v = dp[0] * Wd[c] + dp[1] * Wd[D_ + c] + bd[c];
  } else {
    int i = n - 2;
    const float* lp = loc + ((size_t)b * 1000 + i) * 2;
    v = lp[0] * Wn[c] + lp[1] * Wn[D_ + c] + demand[b * 1000 + i] * Wn[2 * D_ + c] + bn_[c];
  }
  h[idx] = v;
  hb[idx] = (bf16)v;
}

// ---------------- MFMA GEMM: C[M=ROWS, N_] = A[M,K_](bf16) @ W(bf16 [N][K]) ----------------
template<int N_, int K_, bool OUTBF, bool BIAS, bool RELU, bool RES>
__global__ __launch_bounds__(256) void mgemm(
    const bf16* __restrict__ A, const bf16* __restrict__ Wt,
    const float* __restrict__ bias, const float* __restrict__ R, void* __restrict__ Cout) {
  __shared__ bf16 As[64][40];
  __shared__ bf16 Bs[64][40];
  int tid = threadIdx.x;
  int w = tid >> 6, l = tid & 63;
  int bm = blockIdx.y * 64, bn = blockIdx.x * 64;
  int wr = (w >> 1) * 32, wc = (w & 1) * 32;
  f32x4 acc[2][2] = {};
  int sr = tid >> 2, ss = (tid & 3) * 8;
  for (int k0 = 0; k0 < K_; k0 += 32) {
    __syncthreads();
    *(bf16x8*)&As[sr][ss] = *(const bf16x8*)&A[(size_t)(bm + sr) * K_ + k0 + ss];
    *(bf16x8*)&Bs[sr][ss] = *(const bf16x8*)&Wt[(size_t)(bn + sr) * K_ + k0 + ss];
    __syncthreads();
    bf16x8 af[2], bfr[2];
#pragma unroll
    for (int mi = 0; mi < 2; ++mi) af[mi] = *(const bf16x8*)&As[wr + mi * 16 + (l & 15)][(l >> 4) * 8];
#pragma unroll
    for (int ni = 0; ni < 2; ++ni) bfr[ni] = *(const bf16x8*)&Bs[wc + ni * 16 + (l & 15)][(l >> 4) * 8];
#pragma unroll
    for (int mi = 0; mi < 2; ++mi)
#pragma unroll
      for (int ni = 0; ni < 2; ++ni)
        acc[mi][ni] = __builtin_amdgcn_mfma_f32_16x16x32_bf16(af[mi], bfr[ni], acc[mi][ni], 0, 0, 0);
  }
#pragma unroll
  for (int mi = 0; mi < 2; ++mi)
#pragma unroll
    for (int ni = 0; ni < 2; ++ni)
#pragma unroll
      for (int r = 0; r < 4; ++r) {
        int row = bm + wr + mi * 16 + (l >> 4) * 4 + r;
        int col = bn + wc + ni * 16 + (l & 15);
        float v = acc[mi][ni][r];
        if (BIAS) v += bias[col];
        if (RELU) v = fmaxf(v, 0.f);
        if (RES)  v += R[(size_t)row * N_ + col];
        if (OUTBF) ((bf16*)Cout)[(size_t)row * N_ + col] = (bf16)v;
        else       ((float*)Cout)[(size_t)row * N_ + col] = v;
      }
}

// ---------------- MFMA flash attention ----------------
// qkv bf16 [ROWS][384]: q 0:128, k 128:256, v 256:384; head hd -> sub-cols hd*16..+16
// block: one (b,hd), 128 q rows (4 waves x 32); out ab bf16 [ROWS][128]
__global__ __launch_bounds__(256) void mattn(const bf16* __restrict__ qkv, bf16* __restrict__ ab) {
  __shared__ bf16 Ks[64][24];
  __shared__ bf16 Vt[16][72];
  __shared__ bf16 Ps[4][32][72];
  __shared__ float corrW[4][32];
  __shared__ float invW[4][32];
  int tid = threadIdx.x;
  int w = tid >> 6, l = tid & 63;
  int b = blockIdx.x >> 3, hd = blockIdx.x & 7;
  size_t rb = (size_t)b * NT_;
  int qbase = blockIdx.y * 128 + w * 32;

  // Q fragment (B operand of swapped QK^T): lane l -> Q[q=l&31][dk=(l>>5)*8 + j]
  int qrow = qbase + (l & 31); if (qrow >= NT_) qrow = NT_ - 1;
  bf16x8 qf = *(const bf16x8*)&qkv[(rb + qrow) * 384 + hd * 16 + (l >> 5) * 8];

  float m = -1e30f, lsum = 0.f;
  f32x4 oacc[2] = {};
  const f32x16 zz = {0,0,0,0,0,0,0,0,0,0,0,0,0,0,0,0};

  for (int t = 0; t < 16; ++t) {
    int kb = t * 64;
    __syncthreads();
    // stage K (threads 0..127) and V^T (threads 128..255)
    if (tid < 128) {
      int r = tid >> 1, sg = (tid & 1) * 8;
      int krow = kb + r; if (krow >= NT_) krow = NT_ - 1;
      *(bf16x8*)&Ks[r][sg] = *(const bf16x8*)&qkv[(rb + krow) * 384 + 128 + hd * 16 + sg];
    } else {
      int u = tid - 128;
      int r = u >> 1, sg = (u & 1) * 8;
      int krow = kb + r; if (krow >= NT_) krow = NT_ - 1;
      bf16x8 v8 = *(const bf16x8*)&qkv[(rb + krow) * 384 + 256 + hd * 16 + sg];
#pragma unroll
      for (int j = 0; j < 8; ++j) Vt[sg + j][r] = v8[j];
    }
    __syncthreads();

    // S^T = K @ Q^T  (two 32-key subchunks)
    f32x16 sv[2];
#pragma unroll
    for (int c = 0; c < 2; ++c) {
      bf16x8 kf = *(const bf16x8*)&Ks[c * 32 + (l & 31)][(l >> 5) * 8];
      sv[c] = __builtin_amdgcn_mfma_f32_32x32x16_bf16(kf, qf, zz, 0, 0, 0);
    }
    if (kb + 64 > NT_) {  // tail mask
#pragma unroll
      for (int c = 0; c < 2; ++c)
#pragma unroll
        for (int r = 0; r < 16; ++r) {
          int key = kb + c * 32 + (r & 3) + 8 * (r >> 2) + 4 * (l >> 5);
          if (key >= NT_) sv[c][r] = -1e30f;
        }
    }
    // online softmax (q = l&31; this lane holds 32 of the 64 keys, partner l^32 the rest)
    float tm = -1e30f;
#pragma unroll
    for (int c = 0; c < 2; ++c)
#pragma unroll
      for (int r = 0; r < 16; ++r) tm = fmaxf(tm, sv[c][r]);
    tm = fmaxf(tm, __shfl_xor(tm, 32));
    float nm = fmaxf(m, tm);
    float corr = __expf((m - nm) * 0.25f);
    m = nm;
    if (l < 32) corrW[w][l] = corr;
    float ls = 0.f;
#pragma unroll
    for (int c = 0; c < 2; ++c)
#pragma unroll
      for (int r = 0; r < 16; ++r) { float e = __expf((sv[c][r] - m) * 0.25f); sv[c][r] = e; ls += e; }
    lsum = lsum * corr + ls;
    // pack P -> per-wave LDS tile [q 32][key 64]
#pragma unroll
    for (int c = 0; c < 2; ++c)
#pragma unroll
      for (int g2 = 0; g2 < 4; ++g2) {
        bf16x4 pk;
#pragma unroll
        for (int i = 0; i < 4; ++i) pk[i] = (bf16)sv[c][g2 * 4 + i];
        *(bf16x4*)&Ps[w][l & 31][c * 32 + 8 * g2 + 4 * (l >> 5)] = pk;
      }
    // PV: O += P @ V  (rescale old acc by corr first)
    f32x4 cv[2];
#pragma unroll
    for (int g = 0; g < 2; ++g) {
      cv[g] = *(const f32x4*)&corrW[w][g * 16 + (l >> 4) * 4];
#pragma unroll
      for (int r = 0; r < 4; ++r) oacc[g][r] *= cv[g][r];
    }
#pragma unroll
    for (int kh = 0; kh < 2; ++kh) {
      bf16x8 vf = *(const bf16x8*)&Vt[l & 15][kh * 32 + (l >> 4) * 8];
#pragma unroll
      for (int g = 0; g < 2; ++g) {
        bf16x8 pf = *(const bf16x8*)&Ps[w][g * 16 + (l & 15)][kh * 32 + (l >> 4) * 8];
        oacc[g] = __builtin_amdgcn_mfma_f32_16x16x32_bf16(pf, vf, oacc[g], 0, 0, 0);
      }
    }
  }
  // finalize
  lsum = lsum + __shfl_xor(lsum, 32);
  if (l < 32) invW[w][l] = 1.f / lsum;
#pragma unroll
  for (int g = 0; g < 2; ++g) {
    f32x4 iv = *(const f32x4*)&invW[w][g * 16 + (l >> 4) * 4];
#pragma unroll
    for (int r = 0; r < 4; ++r) {
      int qq = qbase + g * 16 + (l >> 4) * 4 + r;
      if (qq < NT_) ab[(rb + qq) * 128 + hd * 16 + (l & 15)] = (bf16)(oacc[g][r] * iv[r]);
    }
  }
}

// ---------------- BN stats (two-stage, deterministic) ----------------
__global__ __launch_bounds__(256) void stats_partial(const float* __restrict__ X,
                                                     float* __restrict__ psum, float* __restrict__ psq) {
  int c = threadIdx.x & 127;
  int half = threadIdx.x >> 7;
  float s = 0.f, q = 0.f;
  for (int rp = blockIdx.x; rp < ROWS / 2; rp += 256) {
    int row = rp * 2 + half;
    float v = X[(size_t)row * D_ + c];
    s += v; q += v * v;
  }
  __shared__ float ss[256], sq2[256];
  ss[threadIdx.x] = s; sq2[threadIdx.x] = q;
  __syncthreads();
  if (threadIdx.x < 128) {
    psum[blockIdx.x * 128 + threadIdx.x] = ss[threadIdx.x] + ss[threadIdx.x + 128];
    psq[blockIdx.x * 128 + threadIdx.x]  = sq2[threadIdx.x] + sq2[threadIdx.x + 128];
  }
}

__global__ void stats_final(const float* __restrict__ psum, const float* __restrict__ psq,
                            float* __restrict__ mi) {
  int c = threadIdx.x;  // 128
  float s = 0.f, q = 0.f;
  for (int p = 0; p < 256; ++p) { s += psum[p * 128 + c]; q += psq[p * 128 + c]; }
  float mean = s * (1.f / (float)ROWS);
  float var = q * (1.f / (float)ROWS) - mean * mean;
  mi[c] = mean;
  mi[128 + c] = rsqrtf(var + 1e-5f);
}

__global__ __launch_bounds__(256) void bn_apply(const float* __restrict__ X, const float* __restrict__ mi,
                                                const float* __restrict__ sc, const float* __restrict__ bi,
                                                float* __restrict__ Y, bf16* __restrict__ Yb) {
  int idx = blockIdx.x * 256 + threadIdx.x;
  if (idx < ROWS * D_) {
    int c = idx & 127;
    float v = sc[c] * (X[idx] - mi[c]) * mi[128 + c] + bi[c];
    Y[idx] = v;
    Yb[idx] = (bf16)v;
  }
}

// ---------------- decoder small kernels ----------------
__global__ void ge_kernel(const float* __restrict__ h, float* __restrict__ ge) {
  int b = blockIdx.x, d = threadIdx.x;
  float s = 0.f;
  for (int n = 0; n < NT_; ++n) s += h[((size_t)b * NT_ + n) * D_ + d];
  ge[b * D_ + d] = s * (1.f / (float)NT_);
}

__global__ void query_kernel(const float* __restrict__ ge, const float* __restrict__ h,
                             const float* __restrict__ Wf, const float* __restrict__ Ws,
                             float* __restrict__ qry) {
  int b = blockIdx.x, d = threadIdx.x;
  float s = 0.f;
  for (int k = 0; k < 128; ++k)
    s += ge[b * D_ + k] * Wf[k * D_ + d] + h[(size_t)b * NT_ * D_ + k] * Ws[k * D_ + d];
  qry[b * D_ + d] = s;
}

// ---------------- pointer step ----------------
__global__ __launch_bounds__(256) void pointer_kernel(
    const float* __restrict__ proj, const float* __restrict__ query,
    const int* __restrict__ mask, const float* __restrict__ Wout,
    float* __restrict__ out) {
  __shared__ float sq[128];
  __shared__ float scomp[8][NT_];
  __shared__ float sgl[128];
  __shared__ float sg2[128];
  __shared__ float slog[NT_];
  __shared__ float red[256];
  __shared__ float hsum[8];
  int b = blockIdx.x;
  int tid = threadIdx.x;
  const float* P = proj + (size_t)b * NT_ * 384;
  const int* Mk = mask + b * NT_;
  if (tid < 128) sq[tid] = query[b * 128 + tid];
  __syncthreads();
  for (int hd = 0; hd < 8; ++hd) {
    for (int n = tid; n < NT_; n += 256) {
      float d = 0.f;
#pragma unroll
      for (int i = 0; i < 16; ++i) d += sq[hd * 16 + i] * P[(size_t)n * 384 + hd * 16 + i];
      scomp[hd][n] = Mk[n] ? NEGV : d * 0.25f;
    }
  }
  __syncthreads();
  for (int hd = 0; hd < 8; ++hd) {
    float mx = -1e30f;
    for (int n = tid; n < NT_; n += 256) mx = fmaxf(mx, scomp[hd][n]);
    red[tid] = mx; __syncthreads();
    for (int s = 128; s > 0; s >>= 1) { if (tid < s) red[tid] = fmaxf(red[tid], red[tid + s]); __syncthreads(); }
    mx = red[0]; __syncthreads();
    float sm = 0.f;
    for (int n = tid; n < NT_; n += 256) { float e = __expf(scomp[hd][n] - mx); scomp[hd][n] = e; sm += e; }
    red[tid] = sm; __syncthreads();
    for (int s = 128; s > 0; s >>= 1) { if (tid < s) red[tid] += red[tid + s]; __syncthreads(); }
    if (tid == 0) hsum[hd] = red[0];
    __syncthreads();
  }
  if (tid < 128) {
    int hd = tid >> 4, i = tid & 15;
    float g = 0.f;
    for (int n = 0; n < NT_; ++n) g += scomp[hd][n] * P[(size_t)n * 384 + 128 + hd * 16 + i];
    sgl[tid] = g / hsum[hd];
  }
  __syncthreads();
  if (tid < 128) {
    float g = 0.f;
    for (int k = 0; k < 128; ++k) g += sgl[k] * Wout[k * 128 + tid];
    sg2[tid] = g;
  }
  __syncthreads();
  for (int n = tid; n < NT_; n += 256) {
    float d = 0.f;
    for (int c = 0; c < 128; ++c) d += sg2[c] * P[(size_t)n * 384 + 256 + c];
    d = 10.f * tanhf(d * 0.088388347648318447f);
    slog[n] = Mk[n] ? NEGV : d;
  }
  __syncthreads();
  float mx = -1e30f;
  for (int n = tid; n < NT_; n += 256) mx = fmaxf(mx, slog[n]);
  red[tid] = mx; __syncthreads();
  for (int s = 128; s > 0; s >>= 1) { if (tid < s) red[tid] = fmaxf(red[tid], red[tid + s]); __syncthreads(); }
  mx = red[0]; __syncthreads();
  float sm = 0.f;
  for (int n = tid; n < NT_; n += 256) sm += __expf(slog[n] - mx);
  red[tid] = sm; __syncthreads();
  for (int s = 128; s > 0; s >>= 1) { if (tid < s) red[tid] += red[tid + s]; __syncthreads(); }
  float lse = mx + logf(red[0]);
  for (int n = tid; n < NT_; n += 256) out[(size_t)b * NT_ + n] = slog[n] - lse;
}

// ---------------- launcher ----------------
extern "C" void kernel_launch(void* const* d_in, const int* in_sizes, int n_in,
                              void* d_out, int out_size, void* d_ws, size_t ws_size,
                              hipStream_t stream) {
  const float* depot        = (const float*)d_in[0];
  const float* loc          = (const float*)d_in[1];
  const float* demand       = (const float*)d_in[2];
  const int*   mask         = (const int*)d_in[3];
  const float* W_init_node  = (const float*)d_in[4];
  const float* b_init_node  = (const float*)d_in[5];
  const float* W_init_depot = (const float*)d_in[6];
  const float* b_init_depot = (const float*)d_in[7];
  const float* enc_Wqkv     = (const float*)d_in[8];
  const float* enc_Wo       = (const float*)d_in[9];
  const float* enc_W1       = (const float*)d_in[10];
  const float* enc_b1       = (const float*)d_in[11];
  const float* enc_W2       = (const float*)d_in[12];
  const float* enc_b2       = (const float*)d_in[13];
  const float* bn1_s        = (const float*)d_in[14];
  const float* bn1_b        = (const float*)d_in[15];
  const float* bn2_s        = (const float*)d_in[16];
  const float* bn2_b        = (const float*)d_in[17];
  const float* W_proj       = (const float*)d_in[18];
  const float* W_fixed      = (const float*)d_in[19];
  const float* W_step       = (const float*)d_in[20];
  const float* W_out        = (const float*)d_in[21];
  float* out = (float*)d_out;

  char* base = (char*)d_ws;
  float* h     = (float*)(base);                       // 16,416,768 B
  bf16*  hb    = (bf16*)(base + 16416768);             //  8,208,384 B
  bf16*  ab    = (bf16*)(base + 24625152);             //  8,208,384 B
  char*  big   = base + 32833536;                      // 57,458,688 B (aliased region)
  bf16*  qkvb  = (bf16*)big;                           // ROWS*384 bf16
  float* xb    = (float*)big;                          // ROWS*128 f32 (aliases qkv; disjoint lifetime)
  float* projf = (float*)big;                          // ROWS*384 f32 (after encoder)
  bf16*  ff1b  = (bf16*)(big + 24625152);              // ROWS*512 bf16
  bf16*  wb    = (bf16*)(base + 90292224);             // 884,736 B
  float* psum  = (float*)(base + 91176960);            // 131,072 B
  float* psq   = (float*)(base + 91308032);            // 131,072 B
  float* mi    = (float*)(base + 91439104);            // 1,024 B
  float* ge    = (float*)(base + 91440128);            // 16,384 B
  float* qry   = (float*)(base + 91456512);            // 16,384 B

  bf16* wt_qkv  = wb;
  bf16* wt_wo   = wb + SZ_QKV;
  bf16* wt_w1   = wb + SZ_QKV + SZ_WO;
  bf16* wt_w2   = wb + SZ_QKV + SZ_WO + SZ_W1;
  bf16* wt_proj = wb + SZ_QKV + SZ_WO + SZ_W1 + SZ_W2;

  prep_w<<<1728, 256, 0, stream>>>(enc_Wqkv, enc_Wo, enc_W1, enc_W2, W_proj, wb);
  init_kernel<<<(ROWS * D_ + 255) / 256, 256, 0, stream>>>(
      depot, loc, demand, W_init_node, b_init_node, W_init_depot, b_init_depot, h, hb);

  for (int l = 0; l < 2; ++l) {
    mgemm<384, 128, true, false, false, false><<<dim3(6, 501), 256, 0, stream>>>(
        hb, wt_qkv + (size_t)l * 384 * 128, nullptr, nullptr, qkvb);
    mattn<<<dim3(256, 8), 256, 0, stream>>>(qkvb, ab);
    mgemm<128, 128, false, false, false, true><<<dim3(2, 501), 256, 0, stream>>>(
        ab, wt_wo + (size_t)l * 128 * 128, nullptr, h, xb);
    stats_partial<<<256, 256, 0, stream>>>(xb, psum, psq);
    stats_final<<<1, 128, 0, stream>>>(psum, psq, mi);
    bn_apply<<<(ROWS * D_ + 255) / 256, 256, 0, stream>>>(xb, mi, bn1_s + l * D_, bn1_b + l * D_, h, hb);
    mgemm<512, 128, true, true, true, false><<<dim3(8, 501), 256, 0, stream>>>(
        hb, wt_w1 + (size_t)l * 512 * 128, enc_b1 + (size_t)l * FF_, nullptr, ff1b);
    mgemm<128, 512, false, true, false, true><<<dim3(2, 501), 256, 0, stream>>>(
        ff1b, wt_w2 + (size_t)l * 128 * 512, enc_b2 + (size_t)l * D_, h, xb);
    stats_partial<<<256, 256, 0, stream>>>(xb, psum, psq);
    stats_final<<<1, 128, 0, stream>>>(psum, psq, mi);
    bn_apply<<<(ROWS * D_ + 255) / 256, 256, 0, stream>>>(xb, mi, bn2_s + l * D_, bn2_b + l * D_, h, hb);
  }

  mgemm<384, 128, false, false, false, false><<<dim3(6, 501), 256, 0, stream>>>(
      hb, wt_proj, nullptr, nullptr, projf);
  ge_kernel<<<32, 128, 0, stream>>>(h, ge);
  query_kernel<<<32, 128, 0, stream>>>(ge, h, W_fixed, W_step, qry);
  pointer_kernel<<<32, 256, 0, stream>>>(projf, qry, mask, W_out, out);
}

// Round 3
// 512.901 us; speedup vs baseline: 2.8493x; 1.1988x over previous
//
#include <hip/hip_runtime.h>

#define B_   32
#define NT_  1002
#define D_   128
#define H_   8
#define FF_  512
#define ROWS (B_ * NT_)          // 32064 = 501*64
#define NEGV (-1e9f)

typedef __bf16 bf16;
typedef __bf16 bf16x8 __attribute__((ext_vector_type(8)));
typedef __bf16 bf16x4 __attribute__((ext_vector_type(4)));
typedef float  f32x4  __attribute__((ext_vector_type(4)));
typedef float  f32x16 __attribute__((ext_vector_type(16)));

// ---------------- weight prep: transpose + convert to bf16 [n][k] ----------------
#define SZ_QKV (2*384*128)
#define SZ_WO  (2*128*128)
#define SZ_W1  (2*512*128)
#define SZ_W2  (2*128*512)
#define SZ_PROJ (384*128)

__global__ __launch_bounds__(256) void prep_w(
    const float* __restrict__ qkv, const float* __restrict__ wo, const float* __restrict__ w1,
    const float* __restrict__ w2, const float* __restrict__ proj, bf16* __restrict__ out) {
  int i = blockIdx.x * 256 + threadIdx.x;
  int j = i;
  float v;
  if (j < SZ_QKV) {
    int l = j / 49152, r = j % 49152; int n = r >> 7, k = r & 127;
    v = qkv[((size_t)l * 128 + k) * 384 + n];
  } else {
    j -= SZ_QKV;
    if (j < SZ_WO) {
      int l = j >> 14, r = j & 16383; int n = r >> 7, k = r & 127;
      v = wo[((size_t)l * 128 + k) * 128 + n];
    } else {
      j -= SZ_WO;
      if (j < SZ_W1) {
        int l = j >> 16, r = j & 65535; int n = r >> 7, k = r & 127;
        v = w1[((size_t)l * 128 + k) * 512 + n];
      } else {
        j -= SZ_W1;
        if (j < SZ_W2) {
          int l = j >> 16, r = j & 65535; int n = r >> 9, k = r & 511;
          v = w2[((size_t)l * 512 + k) * 128 + n];
        } else {
          j -= SZ_W2;
          int n = j >> 7, k = j & 127;
          v = proj[(size_t)k * 384 + n];
        }
      }
    }
  }
  out[i] = (bf16)v;
}

// ---------------- init embeddings (fp32 + bf16 shadow) ----------------
__global__ __launch_bounds__(256) void init_kernel(
    const float* __restrict__ depot, const float* __restrict__ loc, const float* __restrict__ demand,
    const float* __restrict__ Wn, const float* __restrict__ bn_, const float* __restrict__ Wd,
    const float* __restrict__ bd, float* __restrict__ h, bf16* __restrict__ hb) {
  int idx = blockIdx.x * 256 + threadIdx.x;
  if (idx >= ROWS * D_) return;
  int c = idx & 127;
  int row = idx >> 7;
  int b = row / NT_;
  int n = row - b * NT_;
  float v;
  if (n < 2) {
    const float* dp = depot + (b * 2 + n) * 2;
    v = dp[0] * Wd[c] + dp[1] * Wd[D_ + c] + bd[c];
  } else {
    int i = n - 2;
    const float* lp = loc + ((size_t)b * 1000 + i) * 2;
    v = lp[0] * Wn[c] + lp[1] * Wn[D_ + c] + demand[b * 1000 + i] * Wn[2 * D_ + c] + bn_[c];
  }
  h[idx] = v;
  hb[idx] = (bf16)v;
}

// ---------------- MFMA GEMM: C[M=ROWS, N_] = A[M,K_](bf16) @ W(bf16 [N][K]) ----------------
template<int N_, int K_, bool OUTBF, bool BIAS, bool RELU, bool RES>
__global__ __launch_bounds__(256) void mgemm(
    const bf16* __restrict__ A, const bf16* __restrict__ Wt,
    const float* __restrict__ bias, const float* __restrict__ R, void* __restrict__ Cout) {
  __shared__ bf16 As[64][40];
  __shared__ bf16 Bs[64][40];
  int tid = threadIdx.x;
  int w = tid >> 6, l = tid & 63;
  int bm = blockIdx.y * 64, bn = blockIdx.x * 64;
  int wr = (w >> 1) * 32, wc = (w & 1) * 32;
  f32x4 acc[2][2] = {};
  int sr = tid >> 2, ss = (tid & 3) * 8;
  for (int k0 = 0; k0 < K_; k0 += 32) {
    __syncthreads();
    *(bf16x8*)&As[sr][ss] = *(const bf16x8*)&A[(size_t)(bm + sr) * K_ + k0 + ss];
    *(bf16x8*)&Bs[sr][ss] = *(const bf16x8*)&Wt[(size_t)(bn + sr) * K_ + k0 + ss];
    __syncthreads();
    bf16x8 af[2], bfr[2];
#pragma unroll
    for (int mi = 0; mi < 2; ++mi) af[mi] = *(const bf16x8*)&As[wr + mi * 16 + (l & 15)][(l >> 4) * 8];
#pragma unroll
    for (int ni = 0; ni < 2; ++ni) bfr[ni] = *(const bf16x8*)&Bs[wc + ni * 16 + (l & 15)][(l >> 4) * 8];
#pragma unroll
    for (int mi = 0; mi < 2; ++mi)
#pragma unroll
      for (int ni = 0; ni < 2; ++ni)
        acc[mi][ni] = __builtin_amdgcn_mfma_f32_16x16x32_bf16(af[mi], bfr[ni], acc[mi][ni], 0, 0, 0);
  }
#pragma unroll
  for (int mi = 0; mi < 2; ++mi)
#pragma unroll
    for (int ni = 0; ni < 2; ++ni)
#pragma unroll
      for (int r = 0; r < 4; ++r) {
        int row = bm + wr + mi * 16 + (l >> 4) * 4 + r;
        int col = bn + wc + ni * 16 + (l & 15);
        float v = acc[mi][ni][r];
        if (BIAS) v += bias[col];
        if (RELU) v = fmaxf(v, 0.f);
        if (RES)  v += R[(size_t)row * N_ + col];
        if (OUTBF) ((bf16*)Cout)[(size_t)row * N_ + col] = (bf16)v;
        else       ((float*)Cout)[(size_t)row * N_ + col] = v;
      }
}

// ---------------- MFMA flash attention ----------------
__global__ __launch_bounds__(256) void mattn(const bf16* __restrict__ qkv, bf16* __restrict__ ab) {
  __shared__ bf16 Ks[64][24];
  __shared__ bf16 Vt[16][72];
  __shared__ bf16 Ps[4][32][72];
  __shared__ float corrW[4][32];
  __shared__ float invW[4][32];
  int tid = threadIdx.x;
  int w = tid >> 6, l = tid & 63;
  int b = blockIdx.x >> 3, hd = blockIdx.x & 7;
  size_t rb = (size_t)b * NT_;
  int qbase = blockIdx.y * 128 + w * 32;

  int qrow = qbase + (l & 31); if (qrow >= NT_) qrow = NT_ - 1;
  bf16x8 qf = *(const bf16x8*)&qkv[(rb + qrow) * 384 + hd * 16 + (l >> 5) * 8];

  float m = -1e30f, lsum = 0.f;
  f32x4 oacc[2] = {};
  const f32x16 zz = {0,0,0,0,0,0,0,0,0,0,0,0,0,0,0,0};

  for (int t = 0; t < 16; ++t) {
    int kb = t * 64;
    __syncthreads();
    if (tid < 128) {
      int r = tid >> 1, sg = (tid & 1) * 8;
      int krow = kb + r; if (krow >= NT_) krow = NT_ - 1;
      *(bf16x8*)&Ks[r][sg] = *(const bf16x8*)&qkv[(rb + krow) * 384 + 128 + hd * 16 + sg];
    } else {
      int u = tid - 128;
      int r = u >> 1, sg = (u & 1) * 8;
      int krow = kb + r; if (krow >= NT_) krow = NT_ - 1;
      bf16x8 v8 = *(const bf16x8*)&qkv[(rb + krow) * 384 + 256 + hd * 16 + sg];
#pragma unroll
      for (int j = 0; j < 8; ++j) Vt[sg + j][r] = v8[j];
    }
    __syncthreads();

    f32x16 sv[2];
#pragma unroll
    for (int c = 0; c < 2; ++c) {
      bf16x8 kf = *(const bf16x8*)&Ks[c * 32 + (l & 31)][(l >> 5) * 8];
      sv[c] = __builtin_amdgcn_mfma_f32_32x32x16_bf16(kf, qf, zz, 0, 0, 0);
    }
    if (kb + 64 > NT_) {
#pragma unroll
      for (int c = 0; c < 2; ++c)
#pragma unroll
        for (int r = 0; r < 16; ++r) {
          int key = kb + c * 32 + (r & 3) + 8 * (r >> 2) + 4 * (l >> 5);
          if (key >= NT_) sv[c][r] = -1e30f;
        }
    }
    float tm = -1e30f;
#pragma unroll
    for (int c = 0; c < 2; ++c)
#pragma unroll
      for (int r = 0; r < 16; ++r) tm = fmaxf(tm, sv[c][r]);
    tm = fmaxf(tm, __shfl_xor(tm, 32));
    float nm = fmaxf(m, tm);
    float corr = __expf((m - nm) * 0.25f);
    m = nm;
    if (l < 32) corrW[w][l] = corr;
    float ls = 0.f;
#pragma unroll
    for (int c = 0; c < 2; ++c)
#pragma unroll
      for (int r = 0; r < 16; ++r) { float e = __expf((sv[c][r] - m) * 0.25f); sv[c][r] = e; ls += e; }
    lsum = lsum * corr + ls;
#pragma unroll
    for (int c = 0; c < 2; ++c)
#pragma unroll
      for (int g2 = 0; g2 < 4; ++g2) {
        bf16x4 pk;
#pragma unroll
        for (int i = 0; i < 4; ++i) pk[i] = (bf16)sv[c][g2 * 4 + i];
        *(bf16x4*)&Ps[w][l & 31][c * 32 + 8 * g2 + 4 * (l >> 5)] = pk;
      }
    f32x4 cv[2];
#pragma unroll
    for (int g = 0; g < 2; ++g) {
      cv[g] = *(const f32x4*)&corrW[w][g * 16 + (l >> 4) * 4];
#pragma unroll
      for (int r = 0; r < 4; ++r) oacc[g][r] *= cv[g][r];
    }
#pragma unroll
    for (int kh = 0; kh < 2; ++kh) {
      bf16x8 vf = *(const bf16x8*)&Vt[l & 15][kh * 32 + (l >> 4) * 8];
#pragma unroll
      for (int g = 0; g < 2; ++g) {
        bf16x8 pf = *(const bf16x8*)&Ps[w][g * 16 + (l & 15)][kh * 32 + (l >> 4) * 8];
        oacc[g] = __builtin_amdgcn_mfma_f32_16x16x32_bf16(pf, vf, oacc[g], 0, 0, 0);
      }
    }
  }
  lsum = lsum + __shfl_xor(lsum, 32);
  if (l < 32) invW[w][l] = 1.f / lsum;
#pragma unroll
  for (int g = 0; g < 2; ++g) {
    f32x4 iv = *(const f32x4*)&invW[w][g * 16 + (l >> 4) * 4];
#pragma unroll
    for (int r = 0; r < 4; ++r) {
      int qq = qbase + g * 16 + (l >> 4) * 4 + r;
      if (qq < NT_) ab[(rb + qq) * 128 + hd * 16 + (l & 15)] = (bf16)(oacc[g][r] * iv[r]);
    }
  }
}

// ---------------- BN stats (two-stage, deterministic) ----------------
__global__ __launch_bounds__(256) void stats_partial(const float* __restrict__ X,
                                                     float* __restrict__ psum, float* __restrict__ psq) {
  int c = threadIdx.x & 127;
  int half = threadIdx.x >> 7;
  float s = 0.f, q = 0.f;
  for (int rp = blockIdx.x; rp < ROWS / 2; rp += 256) {
    int row = rp * 2 + half;
    float v = X[(size_t)row * D_ + c];
    s += v; q += v * v;
  }
  __shared__ float ss[256], sq2[256];
  ss[threadIdx.x] = s; sq2[threadIdx.x] = q;
  __syncthreads();
  if (threadIdx.x < 128) {
    psum[blockIdx.x * 128 + threadIdx.x] = ss[threadIdx.x] + ss[threadIdx.x + 128];
    psq[blockIdx.x * 128 + threadIdx.x]  = sq2[threadIdx.x] + sq2[threadIdx.x + 128];
  }
}

__global__ void stats_final(const float* __restrict__ psum, const float* __restrict__ psq,
                            float* __restrict__ mi) {
  int c = threadIdx.x;  // 128
  float s = 0.f, q = 0.f;
  for (int p = 0; p < 256; ++p) { s += psum[p * 128 + c]; q += psq[p * 128 + c]; }
  float mean = s * (1.f / (float)ROWS);
  float var = q * (1.f / (float)ROWS) - mean * mean;
  mi[c] = mean;
  mi[128 + c] = rsqrtf(var + 1e-5f);
}

__global__ __launch_bounds__(256) void bn_apply(const float* __restrict__ X, const float* __restrict__ mi,
                                                const float* __restrict__ sc, const float* __restrict__ bi,
                                                float* __restrict__ Y, bf16* __restrict__ Yb) {
  int idx = blockIdx.x * 256 + threadIdx.x;
  if (idx < ROWS * D_) {
    int c = idx & 127;
    float v = sc[c] * (X[idx] - mi[c]) * mi[128 + c] + bi[c];
    Y[idx] = v;
    Yb[idx] = (bf16)v;
  }
}

// ---------------- decoder: graph-embed partial mean ----------------
__global__ void ge_partial(const bf16* __restrict__ hb, float* __restrict__ part) {
  int b = blockIdx.x, ch = blockIdx.y, d = threadIdx.x;  // 32 x 8 blocks, 128 thr
  int n0 = ch * 126, n1 = n0 + 126; if (n1 > NT_) n1 = NT_;
  float s = 0.f;
  for (int n = n0; n < n1; ++n) s += (float)hb[((size_t)b * NT_ + n) * D_ + d];
  part[(b * 8 + ch) * D_ + d] = s;
}

__global__ void query_kernel(const float* __restrict__ part, const float* __restrict__ h,
                             const float* __restrict__ Wf, const float* __restrict__ Ws,
                             float* __restrict__ qry) {
  __shared__ float sge[128], sh0[128];
  int b = blockIdx.x, d = threadIdx.x;  // 32 x 128
  float s = 0.f;
#pragma unroll
  for (int ch = 0; ch < 8; ++ch) s += part[(b * 8 + ch) * D_ + d];
  sge[d] = s * (1.f / (float)NT_);
  sh0[d] = h[(size_t)b * NT_ * D_ + d];
  __syncthreads();
  float q = 0.f;
  for (int k = 0; k < 128; ++k) q += sge[k] * Wf[k * D_ + d] + sh0[k] * Ws[k * D_ + d];
  qry[b * D_ + d] = q;
}

// ---------------- decoder: glimpse per (b,head) ----------------
// proj bf16 [ROWS][384]: K_g 0:128, V_g 128:256, K_logit 256:384
__global__ __launch_bounds__(256) void glimpse_kernel(
    const bf16* __restrict__ proj, const float* __restrict__ qry,
    const int* __restrict__ mask, float* __restrict__ glimpse) {
  int bid = blockIdx.x; int b = bid >> 3, hd = bid & 7;
  int tid = threadIdx.x;
  __shared__ float sq[16];
  __shared__ float sex[NT_];
  __shared__ float rmax[4];
  __shared__ float wacc[4][17];
  if (tid < 16) sq[tid] = qry[b * 128 + hd * 16 + tid];
  __syncthreads();
  const bf16* P = proj + (size_t)b * NT_ * 384;
  const int* Mk = mask + b * NT_;
  float lmax = -1e30f;
#pragma unroll
  for (int it = 0; it < 4; ++it) {
    int n = tid + it * 256;
    if (n < NT_) {
      float c = NEGV;
      if (!Mk[n]) {
        const bf16* kp = &P[(size_t)n * 384 + hd * 16];
        bf16x8 k0 = *(const bf16x8*)kp, k1 = *(const bf16x8*)(kp + 8);
        float d = 0.f;
#pragma unroll
        for (int i = 0; i < 8; ++i) d += sq[i] * (float)k0[i] + sq[8 + i] * (float)k1[i];
        c = d * 0.25f;
      }
      sex[n] = c;
      lmax = fmaxf(lmax, c);
    }
  }
#pragma unroll
  for (int o = 32; o > 0; o >>= 1) lmax = fmaxf(lmax, __shfl_xor(lmax, o));
  if ((tid & 63) == 0) rmax[tid >> 6] = lmax;
  __syncthreads();
  float mx = fmaxf(fmaxf(rmax[0], rmax[1]), fmaxf(rmax[2], rmax[3]));
  float acc[16];
#pragma unroll
  for (int i = 0; i < 16; ++i) acc[i] = 0.f;
  float lsum = 0.f;
#pragma unroll
  for (int it = 0; it < 4; ++it) {
    int n = tid + it * 256;
    if (n < NT_) {
      float e = __expf(sex[n] - mx);
      lsum += e;
      const bf16* vp = &P[(size_t)n * 384 + 128 + hd * 16];
      bf16x8 v0 = *(const bf16x8*)vp, v1 = *(const bf16x8*)(vp + 8);
#pragma unroll
      for (int i = 0; i < 8; ++i) { acc[i] += e * (float)v0[i]; acc[8 + i] += e * (float)v1[i]; }
    }
  }
#pragma unroll
  for (int o = 32; o > 0; o >>= 1) {
    lsum += __shfl_xor(lsum, o);
#pragma unroll
    for (int i = 0; i < 16; ++i) acc[i] += __shfl_xor(acc[i], o);
  }
  if ((tid & 63) == 0) {
    wacc[tid >> 6][16] = lsum;
#pragma unroll
    for (int i = 0; i < 16; ++i) wacc[tid >> 6][i] = acc[i];
  }
  __syncthreads();
  if (tid < 16) {
    float a = wacc[0][tid] + wacc[1][tid] + wacc[2][tid] + wacc[3][tid];
    float L = wacc[0][16] + wacc[1][16] + wacc[2][16] + wacc[3][16];
    glimpse[b * 128 + hd * 16 + tid] = a / L;
  }
}

__global__ void g2_kernel(const float* __restrict__ glimpse, const float* __restrict__ Wout,
                          float* __restrict__ g2) {
  __shared__ float sg[128];
  int b = blockIdx.x, d = threadIdx.x;  // 32 x 128
  sg[d] = glimpse[b * 128 + d];
  __syncthreads();
  float s = 0.f;
  for (int k = 0; k < 128; ++k) s += sg[k] * Wout[k * 128 + d];
  g2[b * 128 + d] = s;
}

__global__ __launch_bounds__(256) void logits_kernel(
    const bf16* __restrict__ proj, const float* __restrict__ g2,
    const int* __restrict__ mask, float* __restrict__ logits) {
  int b = blockIdx.y;
  int n = blockIdx.x * 256 + threadIdx.x;
  __shared__ float sg[128];
  if (threadIdx.x < 128) sg[threadIdx.x] = g2[b * 128 + threadIdx.x];
  __syncthreads();
  if (n >= NT_) return;
  const bf16* kp = &proj[((size_t)b * NT_ + n) * 384 + 256];
  float d = 0.f;
#pragma unroll
  for (int j = 0; j < 16; ++j) {
    bf16x8 v = *(const bf16x8*)&kp[j * 8];
#pragma unroll
    for (int i = 0; i < 8; ++i) d += sg[j * 8 + i] * (float)v[i];
  }
  d = 10.f * tanhf(d * 0.088388347648318447f);
  logits[b * NT_ + n] = mask[b * NT_ + n] ? NEGV : d;
}

__global__ __launch_bounds__(256) void lsm_kernel(const float* __restrict__ logits, float* __restrict__ out) {
  int b = blockIdx.x, tid = threadIdx.x;
  __shared__ float red[256];
  float mx = -1e30f;
  for (int n = tid; n < NT_; n += 256) mx = fmaxf(mx, logits[b * NT_ + n]);
  red[tid] = mx; __syncthreads();
  for (int s = 128; s > 0; s >>= 1) { if (tid < s) red[tid] = fmaxf(red[tid], red[tid + s]); __syncthreads(); }
  mx = red[0]; __syncthreads();
  float sm = 0.f;
  for (int n = tid; n < NT_; n += 256) sm += __expf(logits[b * NT_ + n] - mx);
  red[tid] = sm; __syncthreads();
  for (int s = 128; s > 0; s >>= 1) { if (tid < s) red[tid] += red[tid + s]; __syncthreads(); }
  float lse = mx + logf(red[0]);
  for (int n = tid; n < NT_; n += 256) out[(size_t)b * NT_ + n] = logits[b * NT_ + n] - lse;
}

// ---------------- launcher ----------------
extern "C" void kernel_launch(void* const* d_in, const int* in_sizes, int n_in,
                              void* d_out, int out_size, void* d_ws, size_t ws_size,
                              hipStream_t stream) {
  const float* depot        = (const float*)d_in[0];
  const float* loc          = (const float*)d_in[1];
  const float* demand       = (const float*)d_in[2];
  const int*   mask         = (const int*)d_in[3];
  const float* W_init_node  = (const float*)d_in[4];
  const float* b_init_node  = (const float*)d_in[5];
  const float* W_init_depot = (const float*)d_in[6];
  const float* b_init_depot = (const float*)d_in[7];
  const float* enc_Wqkv     = (const float*)d_in[8];
  const float* enc_Wo       = (const float*)d_in[9];
  const float* enc_W1       = (const float*)d_in[10];
  const float* enc_b1       = (const float*)d_in[11];
  const float* enc_W2       = (const float*)d_in[12];
  const float* enc_b2       = (const float*)d_in[13];
  const float* bn1_s        = (const float*)d_in[14];
  const float* bn1_b        = (const float*)d_in[15];
  const float* bn2_s        = (const float*)d_in[16];
  const float* bn2_b        = (const float*)d_in[17];
  const float* W_proj       = (const float*)d_in[18];
  const float* W_fixed      = (const float*)d_in[19];
  const float* W_step       = (const float*)d_in[20];
  const float* W_out        = (const float*)d_in[21];
  float* out = (float*)d_out;

  char* base = (char*)d_ws;
  float* h     = (float*)(base);                       // 16,416,768 B
  bf16*  hb    = (bf16*)(base + 16416768);             //  8,208,384 B
  bf16*  ab    = (bf16*)(base + 24625152);             //  8,208,384 B
  char*  big   = base + 32833536;                      // 57,458,688 B (aliased region)
  bf16*  qkvb  = (bf16*)big;                           // ROWS*384 bf16
  float* xb    = (float*)big;                          // ROWS*128 f32 (disjoint lifetime)
  bf16*  projb = (bf16*)big;                           // ROWS*384 bf16 (decoder phase)
  bf16*  ff1b  = (bf16*)(big + 24625152);              // ROWS*512 bf16
  bf16*  wb    = (bf16*)(base + 90292224);             // 884,736 B
  float* psum  = (float*)(base + 91176960);            // 131,072 B
  float* psq   = (float*)(base + 91308032);            // 131,072 B
  float* mi    = (float*)(base + 91439104);            // 1,024 B
  float* qry   = (float*)(base + 91440128);            // 16,384 B
  float* glim  = (float*)(base + 91456512);            // 16,384 B
  float* g2    = (float*)(base + 91472896);            // 16,384 B
  float* gep   = psum;                                 // reuse (decoder phase): 256*128 f32
  float* logit = psq;                                  // reuse (decoder phase): 32*1002 f32

  bf16* wt_qkv  = wb;
  bf16* wt_wo   = wb + SZ_QKV;
  bf16* wt_w1   = wb + SZ_QKV + SZ_WO;
  bf16* wt_w2   = wb + SZ_QKV + SZ_WO + SZ_W1;
  bf16* wt_proj = wb + SZ_QKV + SZ_WO + SZ_W1 + SZ_W2;

  prep_w<<<1728, 256, 0, stream>>>(enc_Wqkv, enc_Wo, enc_W1, enc_W2, W_proj, wb);
  init_kernel<<<(ROWS * D_ + 255) / 256, 256, 0, stream>>>(
      depot, loc, demand, W_init_node, b_init_node, W_init_depot, b_init_depot, h, hb);

  for (int l = 0; l < 2; ++l) {
    mgemm<384, 128, true, false, false, false><<<dim3(6, 501), 256, 0, stream>>>(
        hb, wt_qkv + (size_t)l * 384 * 128, nullptr, nullptr, qkvb);
    mattn<<<dim3(256, 8), 256, 0, stream>>>(qkvb, ab);
    mgemm<128, 128, false, false, false, true><<<dim3(2, 501), 256, 0, stream>>>(
        ab, wt_wo + (size_t)l * 128 * 128, nullptr, h, xb);
    stats_partial<<<256, 256, 0, stream>>>(xb, psum, psq);
    stats_final<<<1, 128, 0, stream>>>(psum, psq, mi);
    bn_apply<<<(ROWS * D_ + 255) / 256, 256, 0, stream>>>(xb, mi, bn1_s + l * D_, bn1_b + l * D_, h, hb);
    mgemm<512, 128, true, true, true, false><<<dim3(8, 501), 256, 0, stream>>>(
        hb, wt_w1 + (size_t)l * 512 * 128, enc_b1 + (size_t)l * FF_, nullptr, ff1b);
    mgemm<128, 512, false, true, false, true><<<dim3(2, 501), 256, 0, stream>>>(
        ff1b, wt_w2 + (size_t)l * 128 * 512, enc_b2 + (size_t)l * D_, h, xb);
    stats_partial<<<256, 256, 0, stream>>>(xb, psum, psq);
    stats_final<<<1, 128, 0, stream>>>(psum, psq, mi);
    bn_apply<<<(ROWS * D_ + 255) / 256, 256, 0, stream>>>(xb, mi, bn2_s + l * D_, bn2_b + l * D_, h, hb);
  }

  // decoder
  mgemm<384, 128, true, false, false, false><<<dim3(6, 501), 256, 0, stream>>>(
      hb, wt_proj, nullptr, nullptr, projb);
  ge_partial<<<dim3(32, 8), 128, 0, stream>>>(hb, gep);
  query_kernel<<<32, 128, 0, stream>>>(gep, h, W_fixed, W_step, qry);
  glimpse_kernel<<<256, 256, 0, stream>>>(projb, qry, mask, glim);
  g2_kernel<<<32, 128, 0, stream>>>(glim, W_out, g2);
  logits_kernel<<<dim3(4, 32), 256, 0, stream>>>(projb, g2, mask, logit);
  lsm_kernel<<<32, 256, 0, stream>>>(logit, out);
}